// Round 15
// baseline (515.347 us; speedup 1.0000x reference)
//
#include <hip/hip_runtime.h>
#include <stdint.h>

#define NROWS 32768
#define DDIM  512
#define KCODES 8192
#define CAP 128
// int8 filter: z' = rn(z*16), e' = rn(e*127*8192); dot' exact i32.
// Scaled error sigma ~= 490/pair; margin 5000 = fixed slop + 6.3 sigma (r11-validated).
#define MARGIN_SCALED 5000
#define SZ 16.0f
#define SE 1040384.0f

// ws layout (bytes)
#define OFF_ZQ   0          // 32768*512   = 16777216
#define OFF_EQ   16777216   // 8192*512    = 4194304
#define OFF_RMAX 20971520   // 32768*4
#define OFF_CCNT 21102592   // 32768*4
#define OFF_CIDX 21233664   // 32768*128*4 = 16777216
#define OFF_LOSS 38010880   // 8

typedef __attribute__((ext_vector_type(4))) float floatx4;
typedef __attribute__((ext_vector_type(4))) int   intx4;

__device__ __forceinline__ unsigned fmap(float f) {
    unsigned u = __float_as_uint(f);
    return (u & 0x80000000u) ? ~u : (u | 0x80000000u);
}
__device__ __forceinline__ signed char q8(float v, float s) {
    int x = __float2int_rn(v * s);
    x = x > 127 ? 127 : (x < -127 ? -127 : x);
    return (signed char)x;
}

// ---- phase 0: fused convert (z,emb -> i8) + init (rmax/ccnt/loss) ----
__global__ __launch_bounds__(256) void k_setup(const float* __restrict__ z,
                                               const float* __restrict__ emb,
                                               signed char* __restrict__ zq,
                                               signed char* __restrict__ eq,
                                               int* __restrict__ rmax,
                                               unsigned* __restrict__ ccnt,
                                               double* __restrict__ loss) {
    const int bid = blockIdx.x, t = threadIdx.x;
    {   // z: 8192 blocks x 256 t x 8 = 16777216
        const int i = (bid * 256 + t) * 8;
        floatx4 a = *(const floatx4*)(z + i);
        floatx4 b = *(const floatx4*)(z + i + 4);
        unsigned long long p = 0;
#pragma unroll
        for (int j = 0; j < 4; j++) {
            p |= (unsigned long long)(unsigned char)q8(a[j], SZ) << (8 * j);
            p |= (unsigned long long)(unsigned char)q8(b[j], SZ) << (8 * (j + 4));
        }
        *(unsigned long long*)(zq + i) = p;
    }
    if (bid < 2048) {   // emb: 2048 x 256 x 8 = 4194304
        const int i = (bid * 256 + t) * 8;
        floatx4 a = *(const floatx4*)(emb + i);
        floatx4 b = *(const floatx4*)(emb + i + 4);
        unsigned long long p = 0;
#pragma unroll
        for (int j = 0; j < 4; j++) {
            p |= (unsigned long long)(unsigned char)q8(a[j], SE) << (8 * j);
            p |= (unsigned long long)(unsigned char)q8(b[j], SE) << (8 * (j + 4));
        }
        *(unsigned long long*)(eq + i) = p;
    }
    if (bid < 64) {     // 64 x 256 x 2 = 32768
        const int i = bid * 256 + t;
        rmax[i] = (int)0x80000000; rmax[i + 16384] = (int)0x80000000;
        ccnt[i] = 0u;              ccnt[i + 16384] = 0u;
    }
    if (bid == 0 && t == 0) *loss = 0.0;
}

// ====== phase 1: 128x128 i8 MFMA GEMM (BK=128, 4 K-tiles), 2 blocks/CU co-resident ====
// 256 threads = 4 waves (2M x 2N), wave tile 64x64: acc 4x4 intx4 = 64 + afr 32 + bfr 32.
// LDS 64KB (A 2x16KB + B 2x16KB) -> TWO blocks per CU: independent blocks' phases
// overlap on the CU (m114) -- the structural fix for the 2-phase lockstep stall that
// pinned MfmaUtil at ~19% with the 256^2 1-block/CU config (r12: L2 fixed, time didn't).
// Same 128B-row XOR swizzle both-sides (rule #21); same counted vmcnt(8), never 0 (T4).
// Schedule per K-tile t (buf b): LOADFRAGS(b) -> lgkm0 -> BAR (all waves done reading
// buf b) -> stage 4 units of t+2 into b -> MFMA m01 -> stage 4 more -> MFMA m23 ->
// vmcnt(8) (own t+2 stages in flight => all t+1 landed) -> BAR.
__global__ __launch_bounds__(256, 2) void k_gemm(const signed char* __restrict__ zq,
                                                 const signed char* __restrict__ eq,
                                                 int* __restrict__ rowmaxI,
                                                 unsigned* __restrict__ candCnt,
                                                 unsigned* __restrict__ candIdx) {
    __shared__ signed char lds[65536];    // A: [0,32768) 2x(128x128); B: [32768,65536)
    __shared__ int sMaxI[128];
    __shared__ int sThrI[128];

    const int t = threadIdx.x;
    const int w = t >> 6;                 // wave 0..3
    const int l = t & 63;
    const int wr = w >> 1, wc = w & 1;    // 2M x 2N; wave tile 64 rows x 64 codes
    const int lr = l & 15, lg = l >> 4;

    // XCD-chunked bijective remap: bid = n*8 + xcd; n = codeTi*32 + rowLocal.
    // XCD owns 32 rowT (4096 rows, 2MB i8) for ALL 64 codeT, codeT-outer in time.
    const int bid = blockIdx.x;
    const int xcd = bid & 7, n = bid >> 3;
    const int rowT  = (xcd * 32 + (n & 31)) * 128;   // 256 row tiles, XCD-exclusive
    const int codeT = (n >> 5) * 128;                // 64 code tiles, time-ordered

    // staging: unit = 32 rows x 128B = 4KB = 1 gload16/thread. Units 0..3 A, 4..7 B.
    const int sr   = t >> 3;                      // 0..31 row within unit
    const int sc16 = t & 7;                       // 16B granule
    const int scsw = (sc16 ^ (sr & 7)) * 16;      // pre-swizzled source col (i8 elems)

    intx4 acc[4][4];                              // i32 dots
#pragma unroll
    for (int m = 0; m < 4; m++)
#pragma unroll
        for (int nn = 0; nn < 4; nn++) acc[m][nn] = (intx4){0, 0, 0, 0};

    intx4 afr[4][2];   // A frags: m 0..3, ks 0..1 (16 i8 each)
    intx4 bfr[4][2];   // B frags: nn 0..3, ks 0..1

#define STAGE(kt, unit, bsel)                                                          \
    do {                                                                               \
        const signed char* _g = ((unit) < 4)                                           \
            ? zq + (size_t)(rowT  + (unit) * 32 + sr) * DDIM + (kt) * 128 + scsw       \
            : eq + (size_t)(codeT + ((unit) - 4) * 32 + sr) * DDIM + (kt) * 128 + scsw;\
        signed char* _d = ((unit) < 4)                                                 \
            ? lds + (bsel) * 16384 + ((unit) * 32 + sr) * 128 + sc16 * 16              \
            : lds + 32768 + (bsel) * 16384 + (((unit) - 4) * 32 + sr) * 128 + sc16 * 16;\
        __builtin_amdgcn_global_load_lds(                                              \
            (const __attribute__((address_space(1))) unsigned int*)_g,                 \
            (__attribute__((address_space(3))) unsigned int*)_d, 16, 0, 0);            \
    } while (0)

#define LOADFRAGS(bsel)                                                                \
    do {                                                                               \
        const signed char* _A = lds + (bsel) * 16384;                                  \
        const signed char* _B = lds + 32768 + (bsel) * 16384;                          \
        _Pragma("unroll")                                                              \
        for (int _m = 0; _m < 4; _m++) {                                               \
            const int _row = wr * 64 + _m * 16 + lr;                                   \
            _Pragma("unroll")                                                          \
            for (int _ks = 0; _ks < 2; _ks++)                                          \
                afr[_m][_ks] = *(const intx4*)(_A + _row * 128 +                       \
                                (((_ks * 4 + lg) ^ (lr & 7)) * 16));                   \
        }                                                                              \
        _Pragma("unroll")                                                              \
        for (int _nn = 0; _nn < 4; _nn++) {                                            \
            const int _row = wc * 64 + _nn * 16 + lr;                                  \
            _Pragma("unroll")                                                          \
            for (int _ks = 0; _ks < 2; _ks++)                                          \
                bfr[_nn][_ks] = *(const intx4*)(_B + _row * 128 +                      \
                                (((_ks * 4 + lg) ^ (lr & 7)) * 16));                   \
        }                                                                              \
    } while (0)

#define MFMAH(m0)                                                                      \
    do {                                                                               \
        __builtin_amdgcn_s_setprio(1);                                                 \
        _Pragma("unroll")                                                              \
        for (int _mm = 0; _mm < 2; _mm++)                                              \
            _Pragma("unroll")                                                          \
            for (int _ks = 0; _ks < 2; _ks++)                                          \
                _Pragma("unroll")                                                      \
                for (int _nn = 0; _nn < 4; _nn++)                                      \
                    acc[(m0) + _mm][_nn] = __builtin_amdgcn_mfma_i32_16x16x64_i8(      \
                        afr[(m0) + _mm][_ks], bfr[_nn][_ks], acc[(m0) + _mm][_nn], 0, 0, 0); \
        __builtin_amdgcn_s_setprio(0);                                                 \
    } while (0)

#define BAR() __builtin_amdgcn_s_barrier()
#define LGKM0() do { asm volatile("s_waitcnt lgkmcnt(0)" ::: "memory"); \
                     __builtin_amdgcn_sched_barrier(0); } while (0)
#define VMC8() do { asm volatile("s_waitcnt vmcnt(8)" ::: "memory"); \
                    __builtin_amdgcn_sched_barrier(0); } while (0)
#define CLMP(x) ((x) < 3 ? (x) : 3)

    if (t < 128) sMaxI[t] = (int)0x80000000;

    // prologue: tile0 -> buf0 (8 units), tile1 -> buf1 (8 units); wait tile0 (8 left)
    STAGE(0, 0, 0); STAGE(0, 1, 0); STAGE(0, 2, 0); STAGE(0, 3, 0);
    STAGE(0, 4, 0); STAGE(0, 5, 0); STAGE(0, 6, 0); STAGE(0, 7, 0);
    STAGE(1, 0, 1); STAGE(1, 1, 1); STAGE(1, 2, 1); STAGE(1, 3, 1);
    STAGE(1, 4, 1); STAGE(1, 5, 1); STAGE(1, 6, 1); STAGE(1, 7, 1);
    VMC8();
    BAR();

#pragma unroll 2
    for (int t0 = 0; t0 < 4; ++t0) {
        const int b  = t0 & 1;
        const int nk = CLMP(t0 + 2);
        LOADFRAGS(b);       // all 16 frag reads of tile t0
        LGKM0();
        BAR();              // all waves done reading buf b => region free for t0+2
        STAGE(nk, 0, b); STAGE(nk, 1, b); STAGE(nk, 2, b); STAGE(nk, 3, b);
        MFMAH(0);
        STAGE(nk, 4, b); STAGE(nk, 5, b); STAGE(nk, 6, b); STAGE(nk, 7, b);
        MFMAH(2);
        VMC8();             // own t0+2 stages (8) in flight => all t0+1 units landed
        BAR();
    }

    __syncthreads();   // dangling tail stages only touch lds[], not sMaxI/sThrI

    // ---- epilogue: per-row tile-max (i32 dot) via shfl + LDS atomicMax ----
    // C/D layout: col = lane&15 (code), row = (lane>>4)*4 + j   [dtype-indep, m121-128]
#pragma unroll
    for (int m = 0; m < 4; m++) {
#pragma unroll
        for (int j = 0; j < 4; j++) {
            int v = max(max(acc[m][0][j], acc[m][1][j]),
                        max(acc[m][2][j], acc[m][3][j]));
#pragma unroll
            for (int s = 1; s < 16; s <<= 1) v = max(v, __shfl_xor(v, s, 64));
            if (lr == 0)
                atomicMax(&sMaxI[wr * 64 + m * 16 + lg * 4 + j], v);
        }
    }
    __syncthreads();
    if (t < 128) {
        int g  = rowmaxI[rowT + t];                  // stale-ok running max (same XCD)
        int tm = sMaxI[t];
        sThrI[t] = (tm > g ? tm : g) - MARGIN_SCALED; // superset-safe threshold
        atomicMax(&rowmaxI[rowT + t], tm);           // 1 global atomic per row per block
    }
    __syncthreads();

    // ---- candidate admission: dot >= max(tileMax, runningMax) - margin ----
#pragma unroll
    for (int m = 0; m < 4; m++) {
#pragma unroll
        for (int j = 0; j < 4; j++) {
            const int rl = wr * 64 + m * 16 + lg * 4 + j;
            const int thr = sThrI[rl];
#pragma unroll
            for (int nn = 0; nn < 4; nn++) {
                int d = acc[m][nn][j];
                if (d >= thr) {
                    unsigned pos = atomicAdd(&candCnt[rowT + rl], 1u);
                    if (pos < CAP)
                        candIdx[(size_t)(rowT + rl) * CAP + pos] =
                            (unsigned)(codeT + wc * 64 + nn * 16 + lr);
                }
            }
        }
    }
#undef STAGE
#undef LOADFRAGS
#undef MFMAH
#undef BAR
#undef LGKM0
#undef VMC8
#undef CLMP
}

// ---- phase 2: exact rescore (one wave per row; 8 lane-groups score 8 cands in parallel)
// Per-row f64 loss partial written into the row's OWN candIdx slot AFTER all candidate
// reads -- no cross-block hazard; k_lossred reduces with 64 atomics.
__global__ __launch_bounds__(256) void k_rescore(const float* __restrict__ z,
                                                 const float* __restrict__ emb,
                                                 const unsigned* __restrict__ candCnt,
                                                 unsigned* __restrict__ candIdx,
                                                 float* __restrict__ out) {
    const int w = threadIdx.x >> 6, l = threadIdx.x & 63;
    const int row = blockIdx.x * 4 + w;
    const int g = l >> 3, q = l & 7;     // 8 groups x 8 lanes
    const float* zr = z + (size_t)row * DDIM;

    // old-layout chunk (dims l*8..+7) for s1 (bit-identical to prior rounds) + epilogue
    floatx4 za  = *(const floatx4*)(zr + l * 8);
    floatx4 zb4 = *(const floatx4*)(zr + l * 8 + 4);
    double s1 = 0.0;
#pragma unroll
    for (int j = 0; j < 4; j++) { s1 += (double)za[j] * za[j]; s1 += (double)zb4[j] * zb4[j]; }
#pragma unroll
    for (int s = 1; s < 64; s <<= 1) s1 += __shfl_xor(s1, s, 64);
    const float s1f = (float)s1;

    // scoring layout: lane owns dims q*64..+63 (same for all groups)
    floatx4 zq[16];
#pragma unroll
    for (int k = 0; k < 16; k++) zq[k] = *(const floatx4*)(zr + q * 64 + k * 4);

    auto score = [&](unsigned c) -> unsigned long long {
        const float* er = emb + (size_t)c * DDIM + q * 64;
        double dt = 0.0;
#pragma unroll
        for (int k = 0; k < 16; k++) {
            floatx4 e = *(const floatx4*)(er + k * 4);
            dt += (double)zq[k][0] * (double)e[0];
            dt += (double)zq[k][1] * (double)e[1];
            dt += (double)zq[k][2] * (double)e[2];
            dt += (double)zq[k][3] * (double)e[3];
        }
        dt += __shfl_xor(dt, 1, 64);      // 3-level reduce within 8-lane group
        dt += __shfl_xor(dt, 2, 64);
        dt += __shfl_xor(dt, 4, 64);
        float uf = (float)(2.0 * dt);     // matches fl32(2*M_k) (f64 dot exact to >>f32)
        float df = s1f - uf;              // matches fl32(s1 - 2M) (||e||^2 provably vanishes)
        return ((unsigned long long)fmap(df) << 32) | (unsigned long long)c;
    };

    unsigned cnt = candCnt[row];
    unsigned long long best = ~0ull;
    if (cnt <= CAP) {
        for (unsigned i = g; i < cnt; i += 8) {
            unsigned long long k = score(candIdx[(size_t)row * CAP + i]);
            best = k < best ? k : best;
        }
    } else {  // overflow fallback: exact brute force (deterministic, rare)
        for (unsigned c = g; c < KCODES; c += 8) {
            unsigned long long k = score(c);
            best = k < best ? k : best;
        }
    }
    // cross-group min of (ordered-df, idx) keys -> wave-wide reference argmin
#pragma unroll
    for (int s = 8; s < 64; s <<= 1) {
        unsigned long long o = __shfl_xor(best, s, 64);
        best = o < best ? o : best;
    }
    const unsigned idx = (unsigned)best;  // low 32 bits

    // outputs: quantized_st = z + (q - z) in f32 (exact ST replication), loss partial
    const float* er = emb + (size_t)idx * DDIM + l * 8;
    float* oq = out + 1 + (size_t)row * DDIM + l * 8;   // 4B-aligned only
    double lp = 0.0;
#pragma unroll
    for (int j = 0; j < 8; j++) {
        float zv = (j < 4) ? za[j] : zb4[j - 4];
        float qv = er[j];
        oq[j] = zv + (qv - zv);
        double d = (double)qv - (double)zv;
        lp += d * d;
    }
#pragma unroll
    for (int s = 1; s < 64; s <<= 1) lp += __shfl_xor(lp, s, 64);
    if (l == 0) {
        out[1 + 16777216 + row] = (float)idx;   // indices as f32 values
        // all candidate reads for this row happened above (wave-lockstep) -> safe
        ((double*)(candIdx + (size_t)row * CAP))[0] = lp;
    }
}

// ---- phase 2b: tree-reduce per-row losses (64 blocks, 64 atomics total) ----
__global__ __launch_bounds__(256) void k_lossred(const unsigned* __restrict__ candIdx,
                                                 double* __restrict__ lossAcc) {
    const int tid = blockIdx.x * 256 + threadIdx.x;   // 0..16383
    double s = ((const double*)(candIdx + (size_t)tid * CAP))[0]
             + ((const double*)(candIdx + (size_t)(tid + 16384) * CAP))[0];
#pragma unroll
    for (int sh = 1; sh < 64; sh <<= 1) s += __shfl_xor(s, sh, 64);
    __shared__ double partial[4];
    const int l = threadIdx.x & 63, w = threadIdx.x >> 6;
    if (l == 0) partial[w] = s;
    __syncthreads();
    if (threadIdx.x == 0)
        atomicAdd(lossAcc, partial[0] + partial[1] + partial[2] + partial[3]);
}

// ---- phase 3: finalize loss = 1.25 * mean ----
__global__ void k_final(const double* __restrict__ lossAcc, float* __restrict__ out) {
    if (threadIdx.x == 0 && blockIdx.x == 0)
        out[0] = (float)(1.25 * (*lossAcc) * (1.0 / 16777216.0));
}

extern "C" void kernel_launch(void* const* d_in, const int* in_sizes, int n_in,
                              void* d_out, int out_size, void* d_ws, size_t ws_size,
                              hipStream_t stream) {
    const float* z   = (const float*)d_in[0];
    const float* emb = (const float*)d_in[1];
    float* out = (float*)d_out;
    char* ws = (char*)d_ws;
    signed char* zq = (signed char*)(ws + OFF_ZQ);
    signed char* eq = (signed char*)(ws + OFF_EQ);
    int* rmax = (int*)(ws + OFF_RMAX);
    unsigned* ccnt = (unsigned*)(ws + OFF_CCNT);
    unsigned* cidx = (unsigned*)(ws + OFF_CIDX);
    double* loss = (double*)(ws + OFF_LOSS);

    k_setup<<<dim3(8192), 256, 0, stream>>>(z, emb, zq, eq, rmax, ccnt, loss);
    // linear grid; k_gemm does the XCD-chunked bijective remap internally (T1)
    k_gemm<<<dim3(16384), 256, 0, stream>>>(zq, eq, rmax, ccnt, cidx);
    k_rescore<<<dim3(NROWS / 4), 256, 0, stream>>>(z, emb, ccnt, cidx, out);
    k_lossred<<<dim3(64), 256, 0, stream>>>(cidx, loss);
    k_final<<<dim3(1), 64, 0, stream>>>(loss, out);
}

// Round 16
// 465.157 us; speedup vs baseline: 1.1079x; 1.1079x over previous
//
#include <hip/hip_runtime.h>
#include <stdint.h>

#define NROWS 32768
#define DDIM  512
#define KCODES 8192
#define CAP 128
// int8 filter: z' = rn(z*16), e' = rn(e*127*8192); dot' exact i32.
// Scaled error per (row,code): sigma ~= 490. Margin 5000 = fixed slop + 6.3 sigma
// (r11-validated: candidates ~few/row, rescore cheap; r10's 20000 overflowed CAP).
#define MARGIN_SCALED 5000
#define SZ 16.0f
#define SE 1040384.0f

// ws layout (bytes)
#define OFF_ZQ   0          // 32768*512   = 16777216
#define OFF_EQ   16777216   // 8192*512    = 4194304
#define OFF_RMAX 20971520   // 32768*4
#define OFF_CCNT 21102592   // 32768*4
#define OFF_CIDX 21233664   // 32768*128*4 = 16777216
#define OFF_LOSS 38010880   // 8

typedef __attribute__((ext_vector_type(4))) float floatx4;
typedef __attribute__((ext_vector_type(4))) int   intx4;

__device__ __forceinline__ unsigned fmap(float f) {
    unsigned u = __float_as_uint(f);
    return (u & 0x80000000u) ? ~u : (u | 0x80000000u);
}
__device__ __forceinline__ signed char q8(float v, float s) {
    int x = __float2int_rn(v * s);
    x = x > 127 ? 127 : (x < -127 ? -127 : x);
    return (signed char)x;
}

// ---- phase 0: fused convert (z,emb -> i8) + init (rmax/ccnt/loss) ----
__global__ __launch_bounds__(256) void k_setup(const float* __restrict__ z,
                                               const float* __restrict__ emb,
                                               signed char* __restrict__ zq,
                                               signed char* __restrict__ eq,
                                               int* __restrict__ rmax,
                                               unsigned* __restrict__ ccnt,
                                               double* __restrict__ loss) {
    const int bid = blockIdx.x, t = threadIdx.x;
    {   // z: 8192 blocks x 256 t x 8 = 16777216
        const int i = (bid * 256 + t) * 8;
        floatx4 a = *(const floatx4*)(z + i);
        floatx4 b = *(const floatx4*)(z + i + 4);
        unsigned long long p = 0;
#pragma unroll
        for (int j = 0; j < 4; j++) {
            p |= (unsigned long long)(unsigned char)q8(a[j], SZ) << (8 * j);
            p |= (unsigned long long)(unsigned char)q8(b[j], SZ) << (8 * (j + 4));
        }
        *(unsigned long long*)(zq + i) = p;
    }
    if (bid < 2048) {   // emb: 2048 x 256 x 8 = 4194304
        const int i = (bid * 256 + t) * 8;
        floatx4 a = *(const floatx4*)(emb + i);
        floatx4 b = *(const floatx4*)(emb + i + 4);
        unsigned long long p = 0;
#pragma unroll
        for (int j = 0; j < 4; j++) {
            p |= (unsigned long long)(unsigned char)q8(a[j], SE) << (8 * j);
            p |= (unsigned long long)(unsigned char)q8(b[j], SE) << (8 * (j + 4));
        }
        *(unsigned long long*)(eq + i) = p;
    }
    if (bid < 64) {     // 64 x 256 x 2 = 32768
        const int i = bid * 256 + t;
        rmax[i] = (int)0x80000000; rmax[i + 16384] = (int)0x80000000;
        ccnt[i] = 0u;              ccnt[i + 16384] = 0u;
    }
    if (bid == 0 && t == 0) *loss = 0.0;
}

// ========== phase 1: 256x256 i8 MFMA GEMM (BK=128, 4 K-tiles) + argmax/candidates ====
// r12 verbatim (best measured: 307us, FETCH 27MB, 0 conflicts, no spill).
__global__ __launch_bounds__(512, 2) void k_gemm(const signed char* __restrict__ zq,
                                                 const signed char* __restrict__ eq,
                                                 int* __restrict__ rowmaxI,
                                                 unsigned* __restrict__ candCnt,
                                                 unsigned* __restrict__ candIdx) {
    __shared__ signed char lds[131072];   // A: [0,65536) 2x(256x128); B: [65536,131072)
    __shared__ int sMaxI[256];
    __shared__ int sThrI[256];

    const int t = threadIdx.x;
    const int w = t >> 6;                 // wave 0..7
    const int l = t & 63;
    const int wr = w >> 1, wc = w & 1;    // 4M x 2N; wave tile 64 rows x 128 codes
    const int lr = l & 15, lg = l >> 4;

    // XCD-chunked bijective remap: bid = n*8 + xcd; n = codeTi*16 + rowLocal.
    const int bid = blockIdx.x;
    const int xcd = bid & 7, n = bid >> 3;
    const int rowT  = (xcd * 16 + (n & 15)) * 256;   // 128 row tiles, XCD-exclusive
    const int codeT = (n >> 4) * 256;                // 32 code tiles, time-ordered

    // staging: unit = 64 rows x 128B = 8KB = 1 gload16/thread. Units 0..3 A, 4..7 B.
    const int sr   = t >> 3;                      // 0..63 row within unit
    const int sc16 = t & 7;                       // 16B granule
    const int scsw = (sc16 ^ (sr & 7)) * 16;      // pre-swizzled source col (i8 elems)

    intx4 acc0[4][4], acc1[4][4];                 // n-half 0 / 1 (i32 dots)
#pragma unroll
    for (int m = 0; m < 4; m++)
#pragma unroll
        for (int nn = 0; nn < 4; nn++) {
            acc0[m][nn] = (intx4){0, 0, 0, 0};
            acc1[m][nn] = (intx4){0, 0, 0, 0};
        }

    intx4 afr[4][2];   // A frags: m 0..3, ks 0..1 (16 i8 each; persistent per K-tile)
    intx4 bfr[4][2];   // B frags: nn 0..3, ks 0..1 (reused: half0 then half1)

#define STAGE(kt, unit, bsel)                                                          \
    do {                                                                               \
        const signed char* _g = ((unit) < 4)                                           \
            ? zq + (size_t)(rowT  + (unit) * 64 + sr) * DDIM + (kt) * 128 + scsw       \
            : eq + (size_t)(codeT + ((unit) - 4) * 64 + sr) * DDIM + (kt) * 128 + scsw;\
        signed char* _d = ((unit) < 4)                                                 \
            ? lds + (bsel) * 32768 + ((unit) * 64 + sr) * 128 + sc16 * 16              \
            : lds + 65536 + (bsel) * 32768 + (((unit) - 4) * 64 + sr) * 128 + sc16 * 16;\
        __builtin_amdgcn_global_load_lds(                                              \
            (const __attribute__((address_space(1))) unsigned int*)_g,                 \
            (__attribute__((address_space(3))) unsigned int*)_d, 16, 0, 0);            \
    } while (0)

#define LDA(bsel)                                                                      \
    do {                                                                               \
        const signed char* _A = lds + (bsel) * 32768;                                  \
        _Pragma("unroll")                                                              \
        for (int _m = 0; _m < 4; _m++) {                                               \
            const int _row = wr * 64 + _m * 16 + lr;                                   \
            _Pragma("unroll")                                                          \
            for (int _ks = 0; _ks < 2; _ks++)                                          \
                afr[_m][_ks] = *(const intx4*)(_A + _row * 128 +                       \
                                (((_ks * 4 + lg) ^ (lr & 7)) * 16));                   \
        }                                                                              \
    } while (0)

#define LDB(bsel, h)                                                                   \
    do {                                                                               \
        const signed char* _B = lds + 65536 + (bsel) * 32768;                          \
        _Pragma("unroll")                                                              \
        for (int _nn = 0; _nn < 4; _nn++) {                                            \
            const int _row = wc * 128 + (h) * 64 + _nn * 16 + lr;                      \
            _Pragma("unroll")                                                          \
            for (int _ks = 0; _ks < 2; _ks++)                                          \
                bfr[_nn][_ks] = *(const intx4*)(_B + _row * 128 +                      \
                                (((_ks * 4 + lg) ^ (lr & 7)) * 16));                   \
        }                                                                              \
    } while (0)

#define MFMAH(accH)                                                                    \
    do {                                                                               \
        __builtin_amdgcn_s_setprio(1);                                                 \
        _Pragma("unroll")                                                              \
        for (int _m = 0; _m < 4; _m++)                                                 \
            _Pragma("unroll")                                                          \
            for (int _ks = 0; _ks < 2; _ks++)                                          \
                _Pragma("unroll")                                                      \
                for (int _nn = 0; _nn < 4; _nn++)                                      \
                    accH[_m][_nn] = __builtin_amdgcn_mfma_i32_16x16x64_i8(             \
                        afr[_m][_ks], bfr[_nn][_ks], accH[_m][_nn], 0, 0, 0);          \
        __builtin_amdgcn_s_setprio(0);                                                 \
    } while (0)

#define BAR() __builtin_amdgcn_s_barrier()
#define LGKM0() do { asm volatile("s_waitcnt lgkmcnt(0)" ::: "memory"); \
                     __builtin_amdgcn_sched_barrier(0); } while (0)
#define VMC8() do { asm volatile("s_waitcnt vmcnt(8)" ::: "memory"); \
                    __builtin_amdgcn_sched_barrier(0); } while (0)
#define CLMP(x) ((x) < 3 ? (x) : 3)

    if (t < 256) sMaxI[t] = (int)0x80000000;

    // prologue: tile0 -> buf0 (8 units), tile1 -> buf1 (8 units); wait tile0 (8 left)
    STAGE(0, 0, 0); STAGE(0, 1, 0); STAGE(0, 2, 0); STAGE(0, 3, 0);
    STAGE(0, 4, 0); STAGE(0, 5, 0); STAGE(0, 6, 0); STAGE(0, 7, 0);
    STAGE(1, 0, 1); STAGE(1, 1, 1); STAGE(1, 2, 1); STAGE(1, 3, 1);
    STAGE(1, 4, 1); STAGE(1, 5, 1); STAGE(1, 6, 1); STAGE(1, 7, 1);
    VMC8();
    BAR();

#pragma unroll 2
    for (int t0 = 0; t0 < 4; ++t0) {
        const int b  = t0 & 1;
        const int nk = CLMP(t0 + 2);
        // ph1: frags A(all) + B-low of tile t0; collective-complete; stage 6 units
        LDA(b);
        LDB(b, 0);
        LGKM0();
        BAR();
        STAGE(nk, 0, b); STAGE(nk, 1, b); STAGE(nk, 2, b); STAGE(nk, 3, b);
        STAGE(nk, 4, b); STAGE(nk, 6, b);
        MFMAH(acc0);
        // ph2: frags B-high; collective-complete; stage last 2; MFMA; t0+1 landed; sync
        LDB(b, 1);
        LGKM0();
        BAR();
        STAGE(nk, 5, b); STAGE(nk, 7, b);
        MFMAH(acc1);
        VMC8();
        BAR();
    }

    __syncthreads();

    // ---- epilogue: per-row tile-max (i32 dot) via shfl + LDS atomicMax ----
#pragma unroll
    for (int m = 0; m < 4; m++) {
#pragma unroll
        for (int j = 0; j < 4; j++) {
            int v = max(max(max(acc0[m][0][j], acc0[m][1][j]),
                            max(acc0[m][2][j], acc0[m][3][j])),
                        max(max(acc1[m][0][j], acc1[m][1][j]),
                            max(acc1[m][2][j], acc1[m][3][j])));
#pragma unroll
            for (int s = 1; s < 16; s <<= 1) v = max(v, __shfl_xor(v, s, 64));
            if (lr == 0)
                atomicMax(&sMaxI[wr * 64 + m * 16 + lg * 4 + j], v);
        }
    }
    __syncthreads();
    if (t < 256) {
        int g  = rowmaxI[rowT + t];
        int tm = sMaxI[t];
        sThrI[t] = (tm > g ? tm : g) - MARGIN_SCALED;
        atomicMax(&rowmaxI[rowT + t], tm);
    }
    __syncthreads();

#pragma unroll
    for (int m = 0; m < 4; m++) {
#pragma unroll
        for (int j = 0; j < 4; j++) {
            const int rl = wr * 64 + m * 16 + lg * 4 + j;
            const int thr = sThrI[rl];
#pragma unroll
            for (int h = 0; h < 2; h++) {
#pragma unroll
                for (int nn = 0; nn < 4; nn++) {
                    int d = h ? acc1[m][nn][j] : acc0[m][nn][j];
                    if (d >= thr) {
                        unsigned pos = atomicAdd(&candCnt[rowT + rl], 1u);
                        if (pos < CAP)
                            candIdx[(size_t)(rowT + rl) * CAP + pos] =
                                (unsigned)(codeT + wc * 128 + h * 64 + nn * 16 + lr);
                    }
                }
            }
        }
    }
#undef STAGE
#undef LDA
#undef LDB
#undef MFMAH
#undef BAR
#undef LGKM0
#undef VMC8
#undef CLMP
}

// ---- phase 2: exact rescore (one wave per row; 8 lane-groups score 8 cands in parallel)
__global__ __launch_bounds__(256) void k_rescore(const float* __restrict__ z,
                                                 const float* __restrict__ emb,
                                                 const unsigned* __restrict__ candCnt,
                                                 unsigned* __restrict__ candIdx,
                                                 float* __restrict__ out) {
    const int w = threadIdx.x >> 6, l = threadIdx.x & 63;
    const int row = blockIdx.x * 4 + w;
    const int g = l >> 3, q = l & 7;
    const float* zr = z + (size_t)row * DDIM;

    floatx4 za  = *(const floatx4*)(zr + l * 8);
    floatx4 zb4 = *(const floatx4*)(zr + l * 8 + 4);
    double s1 = 0.0;
#pragma unroll
    for (int j = 0; j < 4; j++) { s1 += (double)za[j] * za[j]; s1 += (double)zb4[j] * zb4[j]; }
#pragma unroll
    for (int s = 1; s < 64; s <<= 1) s1 += __shfl_xor(s1, s, 64);
    const float s1f = (float)s1;

    floatx4 zq[16];
#pragma unroll
    for (int k = 0; k < 16; k++) zq[k] = *(const floatx4*)(zr + q * 64 + k * 4);

    auto score = [&](unsigned c) -> unsigned long long {
        const float* er = emb + (size_t)c * DDIM + q * 64;
        double dt = 0.0;
#pragma unroll
        for (int k = 0; k < 16; k++) {
            floatx4 e = *(const floatx4*)(er + k * 4);
            dt += (double)zq[k][0] * (double)e[0];
            dt += (double)zq[k][1] * (double)e[1];
            dt += (double)zq[k][2] * (double)e[2];
            dt += (double)zq[k][3] * (double)e[3];
        }
        dt += __shfl_xor(dt, 1, 64);
        dt += __shfl_xor(dt, 2, 64);
        dt += __shfl_xor(dt, 4, 64);
        float uf = (float)(2.0 * dt);
        float df = s1f - uf;
        return ((unsigned long long)fmap(df) << 32) | (unsigned long long)c;
    };

    unsigned cnt = candCnt[row];
    unsigned long long best = ~0ull;
    if (cnt <= CAP) {
        for (unsigned i = g; i < cnt; i += 8) {
            unsigned long long k = score(candIdx[(size_t)row * CAP + i]);
            best = k < best ? k : best;
        }
    } else {
        for (unsigned c = g; c < KCODES; c += 8) {
            unsigned long long k = score(c);
            best = k < best ? k : best;
        }
    }
#pragma unroll
    for (int s = 8; s < 64; s <<= 1) {
        unsigned long long o = __shfl_xor(best, s, 64);
        best = o < best ? o : best;
    }
    const unsigned idx = (unsigned)best;

    const float* er = emb + (size_t)idx * DDIM + l * 8;
    float* oq = out + 1 + (size_t)row * DDIM + l * 8;
    double lp = 0.0;
#pragma unroll
    for (int j = 0; j < 8; j++) {
        float zv = (j < 4) ? za[j] : zb4[j - 4];
        float qv = er[j];
        oq[j] = zv + (qv - zv);
        double d = (double)qv - (double)zv;
        lp += d * d;
    }
#pragma unroll
    for (int s = 1; s < 64; s <<= 1) lp += __shfl_xor(lp, s, 64);
    if (l == 0) {
        out[1 + 16777216 + row] = (float)idx;
        ((double*)(candIdx + (size_t)row * CAP))[0] = lp;
    }
}

// ---- phase 2b: tree-reduce per-row losses (64 blocks, 64 atomics total) ----
__global__ __launch_bounds__(256) void k_lossred(const unsigned* __restrict__ candIdx,
                                                 double* __restrict__ lossAcc) {
    const int tid = blockIdx.x * 256 + threadIdx.x;
    double s = ((const double*)(candIdx + (size_t)tid * CAP))[0]
             + ((const double*)(candIdx + (size_t)(tid + 16384) * CAP))[0];
#pragma unroll
    for (int sh = 1; sh < 64; sh <<= 1) s += __shfl_xor(s, sh, 64);
    __shared__ double partial[4];
    const int l = threadIdx.x & 63, w = threadIdx.x >> 6;
    if (l == 0) partial[w] = s;
    __syncthreads();
    if (threadIdx.x == 0)
        atomicAdd(lossAcc, partial[0] + partial[1] + partial[2] + partial[3]);
}

// ---- phase 3: finalize loss = 1.25 * mean ----
__global__ void k_final(const double* __restrict__ lossAcc, float* __restrict__ out) {
    if (threadIdx.x == 0 && blockIdx.x == 0)
        out[0] = (float)(1.25 * (*lossAcc) * (1.0 / 16777216.0));
}

extern "C" void kernel_launch(void* const* d_in, const int* in_sizes, int n_in,
                              void* d_out, int out_size, void* d_ws, size_t ws_size,
                              hipStream_t stream) {
    const float* z   = (const float*)d_in[0];
    const float* emb = (const float*)d_in[1];
    float* out = (float*)d_out;
    char* ws = (char*)d_ws;
    signed char* zq = (signed char*)(ws + OFF_ZQ);
    signed char* eq = (signed char*)(ws + OFF_EQ);
    int* rmax = (int*)(ws + OFF_RMAX);
    unsigned* ccnt = (unsigned*)(ws + OFF_CCNT);
    unsigned* cidx = (unsigned*)(ws + OFF_CIDX);
    double* loss = (double*)(ws + OFF_LOSS);

    k_setup<<<dim3(8192), 256, 0, stream>>>(z, emb, zq, eq, rmax, ccnt, loss);
    k_gemm<<<dim3(4096), 512, 0, stream>>>(zq, eq, rmax, ccnt, cidx);
    k_rescore<<<dim3(NROWS / 4), 256, 0, stream>>>(z, emb, ccnt, cidx, out);
    k_lossred<<<dim3(64), 256, 0, stream>>>(cidx, loss);
    k_final<<<dim3(1), 64, 0, stream>>>(loss, out);
}

// Round 18
// 461.804 us; speedup vs baseline: 1.1159x; 1.0073x over previous
//
#include <hip/hip_runtime.h>
#include <stdint.h>

#define NROWS 32768
#define DDIM  512
#define KCODES 8192
#define CAP 128
// int8 filter: z' = rn(z*16), e' = rn(e*127*8192); dot' exact i32.
// Scaled error per (row,code): sigma ~= 490. Margin 5000 = fixed slop + 6.3 sigma
// (r11-validated: candidates ~few/row, rescore cheap; r10's 20000 overflowed CAP).
#define MARGIN_SCALED 5000
#define SZ 16.0f
#define SE 1040384.0f

// ws layout (bytes)
#define OFF_ZQ   0          // 32768*512   = 16777216
#define OFF_EQ   16777216   // 8192*512    = 4194304
#define OFF_RMAX 20971520   // 32768*4
#define OFF_CCNT 21102592   // 32768*4
#define OFF_CIDX 21233664   // 32768*128*4 = 16777216
#define OFF_LOSS 38010880   // 8

typedef __attribute__((ext_vector_type(4))) float floatx4;
typedef __attribute__((ext_vector_type(4))) int   intx4;

__device__ __forceinline__ unsigned fmap(float f) {
    unsigned u = __float_as_uint(f);
    return (u & 0x80000000u) ? ~u : (u | 0x80000000u);
}
__device__ __forceinline__ signed char q8(float v, float s) {
    int x = __float2int_rn(v * s);
    x = x > 127 ? 127 : (x < -127 ? -127 : x);
    return (signed char)x;
}

// ---- phase 0: fused convert (z,emb -> i8) + init (rmax/ccnt/loss) ----
__global__ __launch_bounds__(256) void k_setup(const float* __restrict__ z,
                                               const float* __restrict__ emb,
                                               signed char* __restrict__ zq,
                                               signed char* __restrict__ eq,
                                               int* __restrict__ rmax,
                                               unsigned* __restrict__ ccnt,
                                               double* __restrict__ loss) {
    const int bid = blockIdx.x, t = threadIdx.x;
    {   // z: 8192 blocks x 256 t x 8 = 16777216
        const int i = (bid * 256 + t) * 8;
        floatx4 a = *(const floatx4*)(z + i);
        floatx4 b = *(const floatx4*)(z + i + 4);
        unsigned long long p = 0;
#pragma unroll
        for (int j = 0; j < 4; j++) {
            p |= (unsigned long long)(unsigned char)q8(a[j], SZ) << (8 * j);
            p |= (unsigned long long)(unsigned char)q8(b[j], SZ) << (8 * (j + 4));
        }
        *(unsigned long long*)(zq + i) = p;
    }
    if (bid < 2048) {   // emb: 2048 x 256 x 8 = 4194304
        const int i = (bid * 256 + t) * 8;
        floatx4 a = *(const floatx4*)(emb + i);
        floatx4 b = *(const floatx4*)(emb + i + 4);
        unsigned long long p = 0;
#pragma unroll
        for (int j = 0; j < 4; j++) {
            p |= (unsigned long long)(unsigned char)q8(a[j], SE) << (8 * j);
            p |= (unsigned long long)(unsigned char)q8(b[j], SE) << (8 * (j + 4));
        }
        *(unsigned long long*)(eq + i) = p;
    }
    if (bid < 64) {     // 64 x 256 x 2 = 32768
        const int i = bid * 256 + t;
        rmax[i] = (int)0x80000000; rmax[i + 16384] = (int)0x80000000;
        ccnt[i] = 0u;              ccnt[i + 16384] = 0u;
    }
    if (bid == 0 && t == 0) *loss = 0.0;
}

// ========== phase 1: 256x256 i8 MFMA GEMM (BK=128, 4 K-tiles) + argmax/candidates ====
// r12 body with ONE change (r17's reordering (b) only; (a) is REVERTED -- it was a
// register-lifetime bug: LDB(b,1) overwrote bfr before MFMAH(acc0) consumed half0):
//   [vmcnt(8); BAR#3] moved BEFORE MFMAH(acc1). acc1's 32 MFMA now share a
//   barrier-free region with the NEXT iteration's LDA+LDB0 ds_reads (tile t+1 is
//   proven landed by the vmcnt) -> drifted waves overlap MFMA with LDS reads.
// All register lifetimes identical to r12: bfr half0 consumed by MFMAH(acc0) BEFORE
// LDB(b,1) overwrites it; stages 5,7 still behind LDB(b,1)'s lgkm0 + BAR#2.
__global__ __launch_bounds__(512, 2) void k_gemm(const signed char* __restrict__ zq,
                                                 const signed char* __restrict__ eq,
                                                 int* __restrict__ rowmaxI,
                                                 unsigned* __restrict__ candCnt,
                                                 unsigned* __restrict__ candIdx) {
    __shared__ signed char lds[131072];   // A: [0,65536) 2x(256x128); B: [65536,131072)
    __shared__ int sMaxI[256];
    __shared__ int sThrI[256];

    const int t = threadIdx.x;
    const int w = t >> 6;                 // wave 0..7
    const int l = t & 63;
    const int wr = w >> 1, wc = w & 1;    // 4M x 2N; wave tile 64 rows x 128 codes
    const int lr = l & 15, lg = l >> 4;

    // XCD-chunked bijective remap: bid = n*8 + xcd; n = codeTi*16 + rowLocal.
    const int bid = blockIdx.x;
    const int xcd = bid & 7, n = bid >> 3;
    const int rowT  = (xcd * 16 + (n & 15)) * 256;   // 128 row tiles, XCD-exclusive
    const int codeT = (n >> 4) * 256;                // 32 code tiles, time-ordered

    // staging: unit = 64 rows x 128B = 8KB = 1 gload16/thread. Units 0..3 A, 4..7 B.
    const int sr   = t >> 3;                      // 0..63 row within unit
    const int sc16 = t & 7;                       // 16B granule
    const int scsw = (sc16 ^ (sr & 7)) * 16;      // pre-swizzled source col (i8 elems)

    intx4 acc0[4][4], acc1[4][4];                 // n-half 0 / 1 (i32 dots)
#pragma unroll
    for (int m = 0; m < 4; m++)
#pragma unroll
        for (int nn = 0; nn < 4; nn++) {
            acc0[m][nn] = (intx4){0, 0, 0, 0};
            acc1[m][nn] = (intx4){0, 0, 0, 0};
        }

    intx4 afr[4][2];   // A frags: m 0..3, ks 0..1 (16 i8 each; persistent per K-tile)
    intx4 bfr[4][2];   // B frags: nn 0..3, ks 0..1 (reused: half0 then half1)

#define STAGE(kt, unit, bsel)                                                          \
    do {                                                                               \
        const signed char* _g = ((unit) < 4)                                           \
            ? zq + (size_t)(rowT  + (unit) * 64 + sr) * DDIM + (kt) * 128 + scsw       \
            : eq + (size_t)(codeT + ((unit) - 4) * 64 + sr) * DDIM + (kt) * 128 + scsw;\
        signed char* _d = ((unit) < 4)                                                 \
            ? lds + (bsel) * 32768 + ((unit) * 64 + sr) * 128 + sc16 * 16              \
            : lds + 65536 + (bsel) * 32768 + (((unit) - 4) * 64 + sr) * 128 + sc16 * 16;\
        __builtin_amdgcn_global_load_lds(                                              \
            (const __attribute__((address_space(1))) unsigned int*)_g,                 \
            (__attribute__((address_space(3))) unsigned int*)_d, 16, 0, 0);            \
    } while (0)

#define LDA(bsel)                                                                      \
    do {                                                                               \
        const signed char* _A = lds + (bsel) * 32768;                                  \
        _Pragma("unroll")                                                              \
        for (int _m = 0; _m < 4; _m++) {                                               \
            const int _row = wr * 64 + _m * 16 + lr;                                   \
            _Pragma("unroll")                                                          \
            for (int _ks = 0; _ks < 2; _ks++)                                          \
                afr[_m][_ks] = *(const intx4*)(_A + _row * 128 +                       \
                                (((_ks * 4 + lg) ^ (lr & 7)) * 16));                   \
        }                                                                              \
    } while (0)

#define LDB(bsel, h)                                                                   \
    do {                                                                               \
        const signed char* _B = lds + 65536 + (bsel) * 32768;                          \
        _Pragma("unroll")                                                              \
        for (int _nn = 0; _nn < 4; _nn++) {                                            \
            const int _row = wc * 128 + (h) * 64 + _nn * 16 + lr;                      \
            _Pragma("unroll")                                                          \
            for (int _ks = 0; _ks < 2; _ks++)                                          \
                bfr[_nn][_ks] = *(const intx4*)(_B + _row * 128 +                      \
                                (((_ks * 4 + lg) ^ (lr & 7)) * 16));                   \
        }                                                                              \
    } while (0)

#define MFMAH(accH)                                                                    \
    do {                                                                               \
        __builtin_amdgcn_s_setprio(1);                                                 \
        _Pragma("unroll")                                                              \
        for (int _m = 0; _m < 4; _m++)                                                 \
            _Pragma("unroll")                                                          \
            for (int _ks = 0; _ks < 2; _ks++)                                          \
                _Pragma("unroll")                                                      \
                for (int _nn = 0; _nn < 4; _nn++)                                      \
                    accH[_m][_nn] = __builtin_amdgcn_mfma_i32_16x16x64_i8(             \
                        afr[_m][_ks], bfr[_nn][_ks], accH[_m][_nn], 0, 0, 0);          \
        __builtin_amdgcn_s_setprio(0);                                                 \
    } while (0)

#define BAR() __builtin_amdgcn_s_barrier()
#define LGKM0() do { asm volatile("s_waitcnt lgkmcnt(0)" ::: "memory"); \
                     __builtin_amdgcn_sched_barrier(0); } while (0)
#define VMC8() do { asm volatile("s_waitcnt vmcnt(8)" ::: "memory"); \
                    __builtin_amdgcn_sched_barrier(0); } while (0)
#define CLMP(x) ((x) < 3 ? (x) : 3)

    if (t < 256) sMaxI[t] = (int)0x80000000;

    // prologue: tile0 -> buf0 (8 units), tile1 -> buf1 (8 units); wait tile0 (8 left)
    STAGE(0, 0, 0); STAGE(0, 1, 0); STAGE(0, 2, 0); STAGE(0, 3, 0);
    STAGE(0, 4, 0); STAGE(0, 5, 0); STAGE(0, 6, 0); STAGE(0, 7, 0);
    STAGE(1, 0, 1); STAGE(1, 1, 1); STAGE(1, 2, 1); STAGE(1, 3, 1);
    STAGE(1, 4, 1); STAGE(1, 5, 1); STAGE(1, 6, 1); STAGE(1, 7, 1);
    VMC8();
    BAR();

#pragma unroll 2
    for (int t0 = 0; t0 < 4; ++t0) {
        const int b  = t0 & 1;
        const int nk = CLMP(t0 + 2);
        // ph1: frags A(all) + B-low of tile t0; collective-complete; stage 6 units
        LDA(b);
        LDB(b, 0);
        LGKM0();
        BAR();
        STAGE(nk, 0, b); STAGE(nk, 1, b); STAGE(nk, 2, b); STAGE(nk, 3, b);
        STAGE(nk, 4, b); STAGE(nk, 6, b);
        MFMAH(acc0);        // consumes bfr half0 BEFORE LDB(b,1) overwrites it
        // ph2: frags B-high; collective-complete; stage last 2
        LDB(b, 1);
        LGKM0();
        BAR();              // #2: units 5,7 readers drained -> staging them safe
        STAGE(nk, 5, b); STAGE(nk, 7, b);
        VMC8();             // t0+1 fully landed (in-flight = own 8 stages)
        BAR();              // #3: next iteration's buf b^1 reads legal from here
        MFMAH(acc1);        // overlaps next iter's LDA/LDB0 across drifted waves
    }

    __syncthreads();

    // ---- epilogue: per-row tile-max (i32 dot) via shfl + LDS atomicMax ----
#pragma unroll
    for (int m = 0; m < 4; m++) {
#pragma unroll
        for (int j = 0; j < 4; j++) {
            int v = max(max(max(acc0[m][0][j], acc0[m][1][j]),
                            max(acc0[m][2][j], acc0[m][3][j])),
                        max(max(acc1[m][0][j], acc1[m][1][j]),
                            max(acc1[m][2][j], acc1[m][3][j])));
#pragma unroll
            for (int s = 1; s < 16; s <<= 1) v = max(v, __shfl_xor(v, s, 64));
            if (lr == 0)
                atomicMax(&sMaxI[wr * 64 + m * 16 + lg * 4 + j], v);
        }
    }
    __syncthreads();
    if (t < 256) {
        int g  = rowmaxI[rowT + t];
        int tm = sMaxI[t];
        sThrI[t] = (tm > g ? tm : g) - MARGIN_SCALED;
        atomicMax(&rowmaxI[rowT + t], tm);
    }
    __syncthreads();

#pragma unroll
    for (int m = 0; m < 4; m++) {
#pragma unroll
        for (int j = 0; j < 4; j++) {
            const int rl = wr * 64 + m * 16 + lg * 4 + j;
            const int thr = sThrI[rl];
#pragma unroll
            for (int h = 0; h < 2; h++) {
#pragma unroll
                for (int nn = 0; nn < 4; nn++) {
                    int d = h ? acc1[m][nn][j] : acc0[m][nn][j];
                    if (d >= thr) {
                        unsigned pos = atomicAdd(&candCnt[rowT + rl], 1u);
                        if (pos < CAP)
                            candIdx[(size_t)(rowT + rl) * CAP + pos] =
                                (unsigned)(codeT + wc * 128 + h * 64 + nn * 16 + lr);
                    }
                }
            }
        }
    }
#undef STAGE
#undef LDA
#undef LDB
#undef MFMAH
#undef BAR
#undef LGKM0
#undef VMC8
#undef CLMP
}

// ---- phase 2: exact rescore (one wave per row; 8 lane-groups score 8 cands in parallel)
__global__ __launch_bounds__(256) void k_rescore(const float* __restrict__ z,
                                                 const float* __restrict__ emb,
                                                 const unsigned* __restrict__ candCnt,
                                                 unsigned* __restrict__ candIdx,
                                                 float* __restrict__ out) {
    const int w = threadIdx.x >> 6, l = threadIdx.x & 63;
    const int row = blockIdx.x * 4 + w;
    const int g = l >> 3, q = l & 7;
    const float* zr = z + (size_t)row * DDIM;

    floatx4 za  = *(const floatx4*)(zr + l * 8);
    floatx4 zb4 = *(const floatx4*)(zr + l * 8 + 4);
    double s1 = 0.0;
#pragma unroll
    for (int j = 0; j < 4; j++) { s1 += (double)za[j] * za[j]; s1 += (double)zb4[j] * zb4[j]; }
#pragma unroll
    for (int s = 1; s < 64; s <<= 1) s1 += __shfl_xor(s1, s, 64);
    const float s1f = (float)s1;

    floatx4 zq[16];
#pragma unroll
    for (int k = 0; k < 16; k++) zq[k] = *(const floatx4*)(zr + q * 64 + k * 4);

    auto score = [&](unsigned c) -> unsigned long long {
        const float* er = emb + (size_t)c * DDIM + q * 64;
        double dt = 0.0;
#pragma unroll
        for (int k = 0; k < 16; k++) {
            floatx4 e = *(const floatx4*)(er + k * 4);
            dt += (double)zq[k][0] * (double)e[0];
            dt += (double)zq[k][1] * (double)e[1];
            dt += (double)zq[k][2] * (double)e[2];
            dt += (double)zq[k][3] * (double)e[3];
        }
        dt += __shfl_xor(dt, 1, 64);
        dt += __shfl_xor(dt, 2, 64);
        dt += __shfl_xor(dt, 4, 64);
        float uf = (float)(2.0 * dt);
        float df = s1f - uf;
        return ((unsigned long long)fmap(df) << 32) | (unsigned long long)c;
    };

    unsigned cnt = candCnt[row];
    unsigned long long best = ~0ull;
    if (cnt <= CAP) {
        for (unsigned i = g; i < cnt; i += 8) {
            unsigned long long k = score(candIdx[(size_t)row * CAP + i]);
            best = k < best ? k : best;
        }
    } else {
        for (unsigned c = g; c < KCODES; c += 8) {
            unsigned long long k = score(c);
            best = k < best ? k : best;
        }
    }
#pragma unroll
    for (int s = 8; s < 64; s <<= 1) {
        unsigned long long o = __shfl_xor(best, s, 64);
        best = o < best ? o : best;
    }
    const unsigned idx = (unsigned)best;

    const float* er = emb + (size_t)idx * DDIM + l * 8;
    float* oq = out + 1 + (size_t)row * DDIM + l * 8;
    double lp = 0.0;
#pragma unroll
    for (int j = 0; j < 8; j++) {
        float zv = (j < 4) ? za[j] : zb4[j - 4];
        float qv = er[j];
        oq[j] = zv + (qv - zv);
        double d = (double)qv - (double)zv;
        lp += d * d;
    }
#pragma unroll
    for (int s = 1; s < 64; s <<= 1) lp += __shfl_xor(lp, s, 64);
    if (l == 0) {
        out[1 + 16777216 + row] = (float)idx;
        ((double*)(candIdx + (size_t)row * CAP))[0] = lp;
    }
}

// ---- phase 2b: tree-reduce per-row losses (64 blocks, 64 atomics total) ----
__global__ __launch_bounds__(256) void k_lossred(const unsigned* __restrict__ candIdx,
                                                 double* __restrict__ lossAcc) {
    const int tid = blockIdx.x * 256 + threadIdx.x;
    double s = ((const double*)(candIdx + (size_t)tid * CAP))[0]
             + ((const double*)(candIdx + (size_t)(tid + 16384) * CAP))[0];
#pragma unroll
    for (int sh = 1; sh < 64; sh <<= 1) s += __shfl_xor(s, sh, 64);
    __shared__ double partial[4];
    const int l = threadIdx.x & 63, w = threadIdx.x >> 6;
    if (l == 0) partial[w] = s;
    __syncthreads();
    if (threadIdx.x == 0)
        atomicAdd(lossAcc, partial[0] + partial[1] + partial[2] + partial[3]);
}

// ---- phase 3: finalize loss = 1.25 * mean ----
__global__ void k_final(const double* __restrict__ lossAcc, float* __restrict__ out) {
    if (threadIdx.x == 0 && blockIdx.x == 0)
        out[0] = (float)(1.25 * (*lossAcc) * (1.0 / 16777216.0));
}

extern "C" void kernel_launch(void* const* d_in, const int* in_sizes, int n_in,
                              void* d_out, int out_size, void* d_ws, size_t ws_size,
                              hipStream_t stream) {
    const float* z   = (const float*)d_in[0];
    const float* emb = (const float*)d_in[1];
    float* out = (float*)d_out;
    char* ws = (char*)d_ws;
    signed char* zq = (signed char*)(ws + OFF_ZQ);
    signed char* eq = (signed char*)(ws + OFF_EQ);
    int* rmax = (int*)(ws + OFF_RMAX);
    unsigned* ccnt = (unsigned*)(ws + OFF_CCNT);
    unsigned* cidx = (unsigned*)(ws + OFF_CIDX);
    double* loss = (double*)(ws + OFF_LOSS);

    k_setup<<<dim3(8192), 256, 0, stream>>>(z, emb, zq, eq, rmax, ccnt, loss);
    k_gemm<<<dim3(4096), 512, 0, stream>>>(zq, eq, rmax, ccnt, cidx);
    k_rescore<<<dim3(NROWS / 4), 256, 0, stream>>>(z, emb, ccnt, cidx, out);
    k_lossred<<<dim3(64), 256, 0, stream>>>(cidx, loss);
    k_final<<<dim3(1), 64, 0, stream>>>(loss, out);
}

// Round 19
// 440.274 us; speedup vs baseline: 1.1705x; 1.0489x over previous
//
#include <hip/hip_runtime.h>
#include <stdint.h>

#define NROWS 32768
#define DDIM  512
#define KCODES 8192
#define CAP 128
// int8 filter: z' = rn(z*16), e' = rn(e*127*8192); dot' exact i32.
// Scaled error per (row,code): sigma ~= 490. Margin 5000 = fixed slop + 6.3 sigma
// (r11-validated; 4000 would be 4.9-sigma => ~0.03 expected misses, too tight).
#define MARGIN_SCALED 5000
#define SZ 16.0f
#define SE 1040384.0f

// ws layout (bytes)
#define OFF_ZQ   0          // 32768*512   = 16777216
#define OFF_EQ   16777216   // 8192*512    = 4194304
#define OFF_RMAX 20971520   // 32768*4
#define OFF_CCNT 21102592   // 32768*4
#define OFF_CIDX 21233664   // 32768*128*4 = 16777216
#define OFF_LOSS 38010880   // 8

typedef __attribute__((ext_vector_type(4))) float floatx4;
typedef __attribute__((ext_vector_type(4))) int   intx4;

__device__ __forceinline__ unsigned fmap(float f) {
    unsigned u = __float_as_uint(f);
    return (u & 0x80000000u) ? ~u : (u | 0x80000000u);
}
__device__ __forceinline__ signed char q8(float v, float s) {
    int x = __float2int_rn(v * s);
    x = x > 127 ? 127 : (x < -127 ? -127 : x);
    return (signed char)x;
}

// ---- phase 0: fused convert (z,emb -> i8) + init (rmax/ccnt/loss) ----
__global__ __launch_bounds__(256) void k_setup(const float* __restrict__ z,
                                               const float* __restrict__ emb,
                                               signed char* __restrict__ zq,
                                               signed char* __restrict__ eq,
                                               int* __restrict__ rmax,
                                               unsigned* __restrict__ ccnt,
                                               double* __restrict__ loss) {
    const int bid = blockIdx.x, t = threadIdx.x;
    {   // z: 8192 blocks x 256 t x 8 = 16777216
        const int i = (bid * 256 + t) * 8;
        floatx4 a = *(const floatx4*)(z + i);
        floatx4 b = *(const floatx4*)(z + i + 4);
        unsigned long long p = 0;
#pragma unroll
        for (int j = 0; j < 4; j++) {
            p |= (unsigned long long)(unsigned char)q8(a[j], SZ) << (8 * j);
            p |= (unsigned long long)(unsigned char)q8(b[j], SZ) << (8 * (j + 4));
        }
        *(unsigned long long*)(zq + i) = p;
    }
    if (bid < 2048) {   // emb: 2048 x 256 x 8 = 4194304
        const int i = (bid * 256 + t) * 8;
        floatx4 a = *(const floatx4*)(emb + i);
        floatx4 b = *(const floatx4*)(emb + i + 4);
        unsigned long long p = 0;
#pragma unroll
        for (int j = 0; j < 4; j++) {
            p |= (unsigned long long)(unsigned char)q8(a[j], SE) << (8 * j);
            p |= (unsigned long long)(unsigned char)q8(b[j], SE) << (8 * (j + 4));
        }
        *(unsigned long long*)(eq + i) = p;
    }
    if (bid < 64) {     // 64 x 256 x 2 = 32768
        const int i = bid * 256 + t;
        rmax[i] = (int)0x80000000; rmax[i + 16384] = (int)0x80000000;
        ccnt[i] = 0u;              ccnt[i + 16384] = 0u;
    }
    if (bid == 0 && t == 0) *loss = 0.0;
}

// ========== phase 1: 256x256 i8 MFMA GEMM (BK=128, 4 K-tiles) + argmax/candidates ====
// r18 kernel verbatim (validated 302us, absmax 0): r12 body + [vmcnt(8);BAR#3] hoisted
// before MFMAH(acc1) so acc1's MFMAs overlap the next iteration's LDA/LDB0 ds_reads.
__global__ __launch_bounds__(512, 2) void k_gemm(const signed char* __restrict__ zq,
                                                 const signed char* __restrict__ eq,
                                                 int* __restrict__ rowmaxI,
                                                 unsigned* __restrict__ candCnt,
                                                 unsigned* __restrict__ candIdx) {
    __shared__ signed char lds[131072];   // A: [0,65536) 2x(256x128); B: [65536,131072)
    __shared__ int sMaxI[256];
    __shared__ int sThrI[256];

    const int t = threadIdx.x;
    const int w = t >> 6;                 // wave 0..7
    const int l = t & 63;
    const int wr = w >> 1, wc = w & 1;    // 4M x 2N; wave tile 64 rows x 128 codes
    const int lr = l & 15, lg = l >> 4;

    // XCD-chunked bijective remap: bid = n*8 + xcd; n = codeTi*16 + rowLocal.
    const int bid = blockIdx.x;
    const int xcd = bid & 7, n = bid >> 3;
    const int rowT  = (xcd * 16 + (n & 15)) * 256;   // 128 row tiles, XCD-exclusive
    const int codeT = (n >> 4) * 256;                // 32 code tiles, time-ordered

    // staging: unit = 64 rows x 128B = 8KB = 1 gload16/thread. Units 0..3 A, 4..7 B.
    const int sr   = t >> 3;                      // 0..63 row within unit
    const int sc16 = t & 7;                       // 16B granule
    const int scsw = (sc16 ^ (sr & 7)) * 16;      // pre-swizzled source col (i8 elems)

    intx4 acc0[4][4], acc1[4][4];                 // n-half 0 / 1 (i32 dots)
#pragma unroll
    for (int m = 0; m < 4; m++)
#pragma unroll
        for (int nn = 0; nn < 4; nn++) {
            acc0[m][nn] = (intx4){0, 0, 0, 0};
            acc1[m][nn] = (intx4){0, 0, 0, 0};
        }

    intx4 afr[4][2];   // A frags: m 0..3, ks 0..1 (16 i8 each; persistent per K-tile)
    intx4 bfr[4][2];   // B frags: nn 0..3, ks 0..1 (reused: half0 then half1)

#define STAGE(kt, unit, bsel)                                                          \
    do {                                                                               \
        const signed char* _g = ((unit) < 4)                                           \
            ? zq + (size_t)(rowT  + (unit) * 64 + sr) * DDIM + (kt) * 128 + scsw       \
            : eq + (size_t)(codeT + ((unit) - 4) * 64 + sr) * DDIM + (kt) * 128 + scsw;\
        signed char* _d = ((unit) < 4)                                                 \
            ? lds + (bsel) * 32768 + ((unit) * 64 + sr) * 128 + sc16 * 16              \
            : lds + 65536 + (bsel) * 32768 + (((unit) - 4) * 64 + sr) * 128 + sc16 * 16;\
        __builtin_amdgcn_global_load_lds(                                              \
            (const __attribute__((address_space(1))) unsigned int*)_g,                 \
            (__attribute__((address_space(3))) unsigned int*)_d, 16, 0, 0);            \
    } while (0)

#define LDA(bsel)                                                                      \
    do {                                                                               \
        const signed char* _A = lds + (bsel) * 32768;                                  \
        _Pragma("unroll")                                                              \
        for (int _m = 0; _m < 4; _m++) {                                               \
            const int _row = wr * 64 + _m * 16 + lr;                                   \
            _Pragma("unroll")                                                          \
            for (int _ks = 0; _ks < 2; _ks++)                                          \
                afr[_m][_ks] = *(const intx4*)(_A + _row * 128 +                       \
                                (((_ks * 4 + lg) ^ (lr & 7)) * 16));                   \
        }                                                                              \
    } while (0)

#define LDB(bsel, h)                                                                   \
    do {                                                                               \
        const signed char* _B = lds + 65536 + (bsel) * 32768;                          \
        _Pragma("unroll")                                                              \
        for (int _nn = 0; _nn < 4; _nn++) {                                            \
            const int _row = wc * 128 + (h) * 64 + _nn * 16 + lr;                      \
            _Pragma("unroll")                                                          \
            for (int _ks = 0; _ks < 2; _ks++)                                          \
                bfr[_nn][_ks] = *(const intx4*)(_B + _row * 128 +                      \
                                (((_ks * 4 + lg) ^ (lr & 7)) * 16));                   \
        }                                                                              \
    } while (0)

#define MFMAH(accH)                                                                    \
    do {                                                                               \
        __builtin_amdgcn_s_setprio(1);                                                 \
        _Pragma("unroll")                                                              \
        for (int _m = 0; _m < 4; _m++)                                                 \
            _Pragma("unroll")                                                          \
            for (int _ks = 0; _ks < 2; _ks++)                                          \
                _Pragma("unroll")                                                      \
                for (int _nn = 0; _nn < 4; _nn++)                                      \
                    accH[_m][_nn] = __builtin_amdgcn_mfma_i32_16x16x64_i8(             \
                        afr[_m][_ks], bfr[_nn][_ks], accH[_m][_nn], 0, 0, 0);          \
        __builtin_amdgcn_s_setprio(0);                                                 \
    } while (0)

#define BAR() __builtin_amdgcn_s_barrier()
#define LGKM0() do { asm volatile("s_waitcnt lgkmcnt(0)" ::: "memory"); \
                     __builtin_amdgcn_sched_barrier(0); } while (0)
#define VMC8() do { asm volatile("s_waitcnt vmcnt(8)" ::: "memory"); \
                    __builtin_amdgcn_sched_barrier(0); } while (0)
#define CLMP(x) ((x) < 3 ? (x) : 3)

    if (t < 256) sMaxI[t] = (int)0x80000000;

    // prologue: tile0 -> buf0 (8 units), tile1 -> buf1 (8 units); wait tile0 (8 left)
    STAGE(0, 0, 0); STAGE(0, 1, 0); STAGE(0, 2, 0); STAGE(0, 3, 0);
    STAGE(0, 4, 0); STAGE(0, 5, 0); STAGE(0, 6, 0); STAGE(0, 7, 0);
    STAGE(1, 0, 1); STAGE(1, 1, 1); STAGE(1, 2, 1); STAGE(1, 3, 1);
    STAGE(1, 4, 1); STAGE(1, 5, 1); STAGE(1, 6, 1); STAGE(1, 7, 1);
    VMC8();
    BAR();

#pragma unroll 2
    for (int t0 = 0; t0 < 4; ++t0) {
        const int b  = t0 & 1;
        const int nk = CLMP(t0 + 2);
        // ph1: frags A(all) + B-low of tile t0; collective-complete; stage 6 units
        LDA(b);
        LDB(b, 0);
        LGKM0();
        BAR();
        STAGE(nk, 0, b); STAGE(nk, 1, b); STAGE(nk, 2, b); STAGE(nk, 3, b);
        STAGE(nk, 4, b); STAGE(nk, 6, b);
        MFMAH(acc0);        // consumes bfr half0 BEFORE LDB(b,1) overwrites it
        // ph2: frags B-high; collective-complete; stage last 2
        LDB(b, 1);
        LGKM0();
        BAR();              // #2: units 5,7 readers drained -> staging them safe
        STAGE(nk, 5, b); STAGE(nk, 7, b);
        VMC8();             // t0+1 fully landed (in-flight = own 8 stages)
        BAR();              // #3: next iteration's buf b^1 reads legal from here
        MFMAH(acc1);        // overlaps next iter's LDA/LDB0 across drifted waves
    }

    __syncthreads();

    // ---- epilogue: per-row tile-max (i32 dot) via shfl + LDS atomicMax ----
#pragma unroll
    for (int m = 0; m < 4; m++) {
#pragma unroll
        for (int j = 0; j < 4; j++) {
            int v = max(max(max(acc0[m][0][j], acc0[m][1][j]),
                            max(acc0[m][2][j], acc0[m][3][j])),
                        max(max(acc1[m][0][j], acc1[m][1][j]),
                            max(acc1[m][2][j], acc1[m][3][j])));
#pragma unroll
            for (int s = 1; s < 16; s <<= 1) v = max(v, __shfl_xor(v, s, 64));
            if (lr == 0)
                atomicMax(&sMaxI[wr * 64 + m * 16 + lg * 4 + j], v);
        }
    }
    __syncthreads();
    if (t < 256) {
        int g  = rowmaxI[rowT + t];
        int tm = sMaxI[t];
        sThrI[t] = (tm > g ? tm : g) - MARGIN_SCALED;
        atomicMax(&rowmaxI[rowT + t], tm);
    }
    __syncthreads();

#pragma unroll
    for (int m = 0; m < 4; m++) {
#pragma unroll
        for (int j = 0; j < 4; j++) {
            const int rl = wr * 64 + m * 16 + lg * 4 + j;
            const int thr = sThrI[rl];
#pragma unroll
            for (int h = 0; h < 2; h++) {
#pragma unroll
                for (int nn = 0; nn < 4; nn++) {
                    int d = h ? acc1[m][nn][j] : acc0[m][nn][j];
                    if (d >= thr) {
                        unsigned pos = atomicAdd(&candCnt[rowT + rl], 1u);
                        if (pos < CAP)
                            candIdx[(size_t)(rowT + rl) * CAP + pos] =
                                (unsigned)(codeT + wc * 128 + h * 64 + nn * 16 + lr);
                    }
                }
            }
        }
    }
#undef STAGE
#undef LDA
#undef LDB
#undef MFMAH
#undef BAR
#undef LGKM0
#undef VMC8
#undef CLMP
}

// ---- phase 2: exact rescore -- TWO rows per wave (32-lane halves; 4 groups x 8 lanes
// per row). Same 8-lane-group scoring math as r18 (q = lane&7 owns dims q*64..+63);
// cross-group reduce s=8,16 and s1/loss reduces s=1..16 stay within the half (XOR
// with s<32 preserves lane>>5). Halves total waves 32768->16384 at equal per-wave
// latency => ~2x fewer latency generations for this latency-bound kernel.
// Per-row f64 loss partial written into the row's OWN candIdx slot AFTER all candidate
// reads (wave-lockstep: divergent per-half loops finish before the epilogue).
__global__ __launch_bounds__(256) void k_rescore(const float* __restrict__ z,
                                                 const float* __restrict__ emb,
                                                 const unsigned* __restrict__ candCnt,
                                                 unsigned* __restrict__ candIdx,
                                                 float* __restrict__ out) {
    const int w = threadIdx.x >> 6, l = threadIdx.x & 63;
    const int hf = l >> 5;                 // half 0/1 -> own row
    const int lh = l & 31;                 // lane within half
    const int row = blockIdx.x * 8 + w * 2 + hf;
    const int g = lh >> 3, q = lh & 7;     // 4 groups x 8 lanes per row
    const float* zr = z + (size_t)row * DDIM;

    // s1 chunk: lane owns dims lh*16..+15 (also reused for the ST/loss epilogue)
    floatx4 zc[4];
#pragma unroll
    for (int c4 = 0; c4 < 4; c4++) zc[c4] = *(const floatx4*)(zr + lh * 16 + c4 * 4);
    double s1 = 0.0;
#pragma unroll
    for (int c4 = 0; c4 < 4; c4++)
#pragma unroll
        for (int j = 0; j < 4; j++) s1 += (double)zc[c4][j] * zc[c4][j];
#pragma unroll
    for (int s = 1; s < 32; s <<= 1) s1 += __shfl_xor(s1, s, 64);   // within-half sum
    const float s1f = (float)s1;

    // scoring layout: lane owns dims q*64..+63 of its row (identical math to r18)
    floatx4 zq[16];
#pragma unroll
    for (int k = 0; k < 16; k++) zq[k] = *(const floatx4*)(zr + q * 64 + k * 4);

    auto score = [&](unsigned c) -> unsigned long long {
        const float* er = emb + (size_t)c * DDIM + q * 64;
        double dt = 0.0;
#pragma unroll
        for (int k = 0; k < 16; k++) {
            floatx4 e = *(const floatx4*)(er + k * 4);
            dt += (double)zq[k][0] * (double)e[0];
            dt += (double)zq[k][1] * (double)e[1];
            dt += (double)zq[k][2] * (double)e[2];
            dt += (double)zq[k][3] * (double)e[3];
        }
        dt += __shfl_xor(dt, 1, 64);      // 3-level reduce within 8-lane group
        dt += __shfl_xor(dt, 2, 64);
        dt += __shfl_xor(dt, 4, 64);
        float uf = (float)(2.0 * dt);     // matches fl32(2*M_k)
        float df = s1f - uf;              // matches fl32(s1 - 2M)
        return ((unsigned long long)fmap(df) << 32) | (unsigned long long)c;
    };

    unsigned cnt = candCnt[row];
    unsigned long long best = ~0ull;
    if (cnt <= CAP) {
        for (unsigned i = g; i < cnt; i += 4) {        // 4 groups per row
            unsigned long long k = score(candIdx[(size_t)row * CAP + i]);
            best = k < best ? k : best;
        }
    } else {  // overflow fallback: exact brute force (deterministic, rare)
        for (unsigned c = g; c < KCODES; c += 4) {
            unsigned long long k = score(c);
            best = k < best ? k : best;
        }
    }
    // cross-group min within the half (s=8,16 stay inside the 32-lane half)
#pragma unroll
    for (int s = 8; s < 32; s <<= 1) {
        unsigned long long o = __shfl_xor(best, s, 64);
        best = o < best ? o : best;
    }
    const unsigned idx = (unsigned)best;  // low 32 bits (valid in every lane of half)

    // outputs: quantized_st = z + (q - z) in f32 (exact ST replication), loss partial
    const float* er = emb + (size_t)idx * DDIM + lh * 16;
    float* oq = out + 1 + (size_t)row * DDIM + lh * 16;   // 4B-aligned only
    double lp = 0.0;
#pragma unroll
    for (int c4 = 0; c4 < 4; c4++) {
        floatx4 ev = *(const floatx4*)(er + c4 * 4);
#pragma unroll
        for (int j = 0; j < 4; j++) {
            float zv = zc[c4][j];
            float qv = ev[j];
            oq[c4 * 4 + j] = zv + (qv - zv);
            double d = (double)qv - (double)zv;
            lp += d * d;
        }
    }
#pragma unroll
    for (int s = 1; s < 32; s <<= 1) lp += __shfl_xor(lp, s, 64);   // within-half sum
    if (lh == 0) {
        out[1 + 16777216 + row] = (float)idx;   // indices as f32 values
        // all candidate reads for this row happened above (wave-lockstep) -> safe
        ((double*)(candIdx + (size_t)row * CAP))[0] = lp;
    }
}

// ---- phase 2b: tree-reduce per-row losses (64 blocks, 64 atomics total) ----
__global__ __launch_bounds__(256) void k_lossred(const unsigned* __restrict__ candIdx,
                                                 double* __restrict__ lossAcc) {
    const int tid = blockIdx.x * 256 + threadIdx.x;
    double s = ((const double*)(candIdx + (size_t)tid * CAP))[0]
             + ((const double*)(candIdx + (size_t)(tid + 16384) * CAP))[0];
#pragma unroll
    for (int sh = 1; sh < 64; sh <<= 1) s += __shfl_xor(s, sh, 64);
    __shared__ double partial[4];
    const int l = threadIdx.x & 63, w = threadIdx.x >> 6;
    if (l == 0) partial[w] = s;
    __syncthreads();
    if (threadIdx.x == 0)
        atomicAdd(lossAcc, partial[0] + partial[1] + partial[2] + partial[3]);
}

// ---- phase 3: finalize loss = 1.25 * mean ----
__global__ void k_final(const double* __restrict__ lossAcc, float* __restrict__ out) {
    if (threadIdx.x == 0 && blockIdx.x == 0)
        out[0] = (float)(1.25 * (*lossAcc) * (1.0 / 16777216.0));
}

extern "C" void kernel_launch(void* const* d_in, const int* in_sizes, int n_in,
                              void* d_out, int out_size, void* d_ws, size_t ws_size,
                              hipStream_t stream) {
    const float* z   = (const float*)d_in[0];
    const float* emb = (const float*)d_in[1];
    float* out = (float*)d_out;
    char* ws = (char*)d_ws;
    signed char* zq = (signed char*)(ws + OFF_ZQ);
    signed char* eq = (signed char*)(ws + OFF_EQ);
    int* rmax = (int*)(ws + OFF_RMAX);
    unsigned* ccnt = (unsigned*)(ws + OFF_CCNT);
    unsigned* cidx = (unsigned*)(ws + OFF_CIDX);
    double* loss = (double*)(ws + OFF_LOSS);

    k_setup<<<dim3(8192), 256, 0, stream>>>(z, emb, zq, eq, rmax, ccnt, loss);
    k_gemm<<<dim3(4096), 512, 0, stream>>>(zq, eq, rmax, ccnt, cidx);
    k_rescore<<<dim3(NROWS / 8), 256, 0, stream>>>(z, emb, ccnt, cidx, out);
    k_lossred<<<dim3(64), 256, 0, stream>>>(cidx, loss);
    k_final<<<dim3(1), 64, 0, stream>>>(loss, out);
}